// Round 9
// baseline (273.911 us; speedup 1.0000x reference)
//
#include <hip/hip_runtime.h>
#include <math.h>

namespace {
constexpr int Bn = 4, Rn = 16384, Sn = 128;
constexpr int NRAY = Bn * Rn;          // 65536 rays
constexpr int SI   = Sn - 1;           // 127 intervals
constexpr int RPW  = 8;                // rays per wave (pipelined loop)
// Output layout: tuple concatenated flat in return order
constexpr size_t OFF_RGB   = 0;                                  // [B,R,3]
constexpr size_t OFF_DEPTH = OFF_RGB   + (size_t)NRAY * 3;       // [B,R,1]
constexpr size_t OFF_W     = OFF_DEPTH + (size_t)NRAY;           // [B,R,SI,1]
constexpr size_t OFF_WALL  = OFF_W     + (size_t)NRAY * SI;      // [B,R,SI,1]
constexpr size_t OFF_ALPHA = OFF_WALL  + (size_t)NRAY * SI;      // [B,R,SI,1]
constexpr size_t OFF_DMID  = OFF_ALPHA + (size_t)NRAY * SI;      // [B,R,SI,1]
constexpr float  EPSF      = 1e-10f;
}

// ---- DPP helpers (pure-VALU cross-lane; no LDS/bpermute) ----
template<int CTRL, int ROW_MASK, bool BC>
__device__ __forceinline__ float dpp_mov(float oldv, float src) {
    return __int_as_float(__builtin_amdgcn_update_dpp(
        __float_as_int(oldv), __float_as_int(src), CTRL, ROW_MASK, 0xF, BC));
}

// 64-lane inclusive prefix PRODUCT (GPUOpen scan; bcast row masks REQUIRED).
__device__ __forceinline__ float wave_prefix_prod(float s) {
    s *= dpp_mov<0x111, 0xF, false>(1.0f, s);   // row_shr:1
    s *= dpp_mov<0x112, 0xF, false>(1.0f, s);   // row_shr:2
    s *= dpp_mov<0x114, 0xF, false>(1.0f, s);   // row_shr:4
    s *= dpp_mov<0x118, 0xF, false>(1.0f, s);   // row_shr:8
    s *= dpp_mov<0x142, 0xa, false>(1.0f, s);   // row_bcast:15 -> rows 1,3
    s *= dpp_mov<0x143, 0xc, false>(1.0f, s);   // row_bcast:31 -> rows 2,3
    return s;
}

// 64-lane sum; lane 63 holds the total afterwards.
__device__ __forceinline__ float wave_sum_last(float x) {
    x += dpp_mov<0x111, 0xF, true>(0.0f, x);
    x += dpp_mov<0x112, 0xF, true>(0.0f, x);
    x += dpp_mov<0x114, 0xF, true>(0.0f, x);
    x += dpp_mov<0x118, 0xF, true>(0.0f, x);
    x += dpp_mov<0x142, 0xa, true>(0.0f, x);
    x += dpp_mov<0x143, 0xc, true>(0.0f, x);
    return x;
}

// Inline-asm 8B global load: issue point pinned at source position (volatile
// asm blocks are mutually ordered; the scheduler cannot sink/split them).
__device__ __forceinline__ float2 gload2(const float2* p) {
    float2 r;
    asm volatile("global_load_dwordx2 %0, %1, off" : "=v"(r) : "v"(p));
    return r;
}

// Per-ray math + stores (identical to the verified R3 kernel).
// EVEN = ray index is even -> per-interval base is 8B-aligned -> dwordx2 path.
template<bool EVEN>
__device__ __forceinline__ void compute_store(
    int ray, int lane, bool valid1,
    float2 d, float2 g, float2 c0, float2 c1, float2 c2,
    float* __restrict__ out)
{
    float d2  = dpp_mov<0x130, 0xF, false>(d.x,  d.x);   // wave_shl:1
    float g2  = dpp_mov<0x130, 0xF, false>(g.x,  g.x);
    float cnx = dpp_mov<0x130, 0xF, false>(c0.x, c0.x);
    float cny = dpp_mov<0x130, 0xF, false>(c0.y, c0.y);
    float cnz = dpp_mov<0x130, 0xF, false>(c1.x, c1.x);

    float delta0 = d.y - d.x;
    float dm0    = 0.5f * (d.x + d.y);
    float x0     = 0.5f * (g.x + g.y) - 1.0f;
    float cm0x   = 0.5f * (c0.x + c1.y);
    float cm0y   = 0.5f * (c0.y + c2.x);
    float cm0z   = 0.5f * (c1.x + c2.y);

    float delta1 = valid1 ? (d2 - d.y)            : 0.0f;
    float dm1    = valid1 ? 0.5f * (d.y + d2)     : 0.0f;
    float x1     = valid1 ? (0.5f * (g.y + g2) - 1.0f) : 0.0f;
    float cm1x   = valid1 ? 0.5f * (c1.y + cnx)   : 0.0f;
    float cm1y   = valid1 ? 0.5f * (c2.x + cny)   : 0.0f;
    float cm1z   = valid1 ? 0.5f * (c2.y + cnz)   : 0.0f;

    // alpha = 1 - exp(-softplus(x)*delta) = 1 - 2^(-delta * log2(1+e^x))
    float l0 = __log2f(1.0f + __expf(x0));
    float l1 = __log2f(1.0f + __expf(x1));
    l0 = fminf(l0, 1e30f);                 // guard inf*0 -> NaN when delta==0
    l1 = fminf(l1, 1e30f);
    float E0 = exp2f(-delta0 * l0);        // = 1 - alpha0
    float E1 = exp2f(-delta1 * l1);
    float alpha0 = 1.0f - E0;
    float alpha1 = 1.0f - E1;              // == 0 for lane 63 (delta1=0)
    float t0 = E0 + EPSF;
    float t1 = valid1 ? (E1 + EPSF) : 1.0f;

    float s  = wave_prefix_prod(t0 * t1);
    float T0 = dpp_mov<0x138, 0xF, false>(1.0f, s);   // exclusive; lane0 -> 1.0
    float T1 = T0 * t0;

    float w0 = (alpha0 + EPSF) * T0;
    float w1 = valid1 ? (alpha1 + EPSF) * T1 : 0.0f;

    const size_t base = (size_t)ray * SI + 2 * lane;
    if (EVEN) {
        if (valid1) {
            *reinterpret_cast<float2*>(out + OFF_W     + base) = make_float2(w0, w1);
            *reinterpret_cast<float2*>(out + OFF_WALL  + base) = make_float2(w0, w1);
            *reinterpret_cast<float2*>(out + OFF_ALPHA + base) = make_float2(alpha0, alpha1);
            *reinterpret_cast<float2*>(out + OFF_DMID  + base) = make_float2(dm0, dm1);
        } else {
            out[OFF_W     + base] = w0;
            out[OFF_WALL  + base] = w0;
            out[OFF_ALPHA + base] = alpha0;
            out[OFF_DMID  + base] = dm0;
        }
    } else {
        out[OFF_W     + base] = w0;
        out[OFF_WALL  + base] = w0;
        out[OFF_ALPHA + base] = alpha0;
        out[OFF_DMID  + base] = dm0;
        if (valid1) {
            out[OFF_W     + base + 1] = w1;
            out[OFF_WALL  + base + 1] = w1;
            out[OFF_ALPHA + base + 1] = alpha1;
            out[OFF_DMID  + base + 1] = dm1;
        }
    }

    float wsum = wave_sum_last(w0 + w1);
    float rx   = wave_sum_last(w0 * cm0x + w1 * cm1x);
    float ry   = wave_sum_last(w0 * cm0y + w1 * cm1y);
    float rz   = wave_sum_last(w0 * cm0z + w1 * cm1z);
    float dsum = wave_sum_last(w0 * dm0  + w1 * dm1);

    if (lane == 63) {
        float cd = dsum / (EPSF + wsum);
        if (isnan(cd)) cd = 100.0f;              // nan_to_num(nan=MAX_DEPTH)
        cd = fminf(fmaxf(cd, 0.1f), 100.0f);     // clip; also maps ±inf
        out[OFF_RGB + (size_t)ray * 3 + 0] = rx * 2.0f - 1.0f;
        out[OFF_RGB + (size_t)ray * 3 + 1] = ry * 2.0f - 1.0f;
        out[OFF_RGB + (size_t)ray * 3 + 2] = rz * 2.0f - 1.0f;
        out[OFF_DEPTH + ray] = cd;
    }
}

// Persistent pipelined wave: 8 consecutive rays, steady-state 2-deep pipeline.
//   prologue: issue loads(0)
//   iter k:   issue loads(k+1); s_waitcnt vmcnt(N_k); compute+store(k)
// vmcnt retires in issue order, so N_k = min #vmem-ops issued after loads(k):
//   k=0: loads(1)=5.  k=1..6: stores(k-1)>=10 + loads(k+1)=5 -> 15.
//   k=7: stores(6)>=10 -> 10.
// (store minimum 10/ray is merging-proof: 8 un-mergeable interval stores +
//  rgb merged to dwordx3 + depth. Spills/extras only ADD later ops -> the
//  wait only becomes more conservative, never unsafe.)
// "memory" clobber on the waits keeps stores from crossing count points.
__global__ __launch_bounds__(256) void raymarch_kernel(
    const float* __restrict__ colors,
    const float* __restrict__ dlog,
    const float* __restrict__ depths,
    float* __restrict__ out)
{
    const int wid  = (blockIdx.x * 256 + threadIdx.x) >> 6;   // wave id
    const int lane = threadIdx.x & 63;
    const int ray0 = wid * RPW;
    const bool valid1 = (lane < 63);

    const float2* dp = reinterpret_cast<const float2*>(depths) + (size_t)ray0 * (Sn / 2) + lane;
    const float2* gp = reinterpret_cast<const float2*>(dlog)   + (size_t)ray0 * (Sn / 2) + lane;
    const float2* cp = reinterpret_cast<const float2*>(colors) + (size_t)ray0 * (Sn * 3 / 2) + lane * 3;

    // double-buffered batch registers, statically indexed via literal k
    float2 bd[2], bg[2], bc0[2], bc1[2], bc2[2];

#define ISSUE(k)                                                              \
    do {                                                                      \
        bd [(k) & 1] = gload2(dp + (k) * (Sn / 2));                           \
        bg [(k) & 1] = gload2(gp + (k) * (Sn / 2));                           \
        bc0[(k) & 1] = gload2(cp + (k) * (Sn * 3 / 2) + 0);                   \
        bc1[(k) & 1] = gload2(cp + (k) * (Sn * 3 / 2) + 1);                   \
        bc2[(k) & 1] = gload2(cp + (k) * (Sn * 3 / 2) + 2);                   \
    } while (0)

#define WAITPIN(k, N)                                                         \
    asm volatile("s_waitcnt vmcnt(" #N ")"                                    \
        : "+v"(bd[(k) & 1]), "+v"(bg[(k) & 1]),                               \
          "+v"(bc0[(k) & 1]), "+v"(bc1[(k) & 1]), "+v"(bc2[(k) & 1])          \
        :                                                                     \
        : "memory")

#define CS(k)                                                                 \
    compute_store<(((k) & 1) == 0)>(ray0 + (k), lane, valid1,                 \
        bd[(k) & 1], bg[(k) & 1], bc0[(k) & 1], bc1[(k) & 1], bc2[(k) & 1],   \
        out)

    ISSUE(0);
    ISSUE(1); WAITPIN(0, 5);  CS(0);
    ISSUE(2); WAITPIN(1, 15); CS(1);
    ISSUE(3); WAITPIN(2, 15); CS(2);
    ISSUE(4); WAITPIN(3, 15); CS(3);
    ISSUE(5); WAITPIN(4, 15); CS(4);
    ISSUE(6); WAITPIN(5, 15); CS(5);
    ISSUE(7); WAITPIN(6, 15); CS(6);
              WAITPIN(7, 10); CS(7);

#undef ISSUE
#undef WAITPIN
#undef CS
}

extern "C" void kernel_launch(void* const* d_in, const int* in_sizes, int n_in,
                              void* d_out, int out_size, void* d_ws, size_t ws_size,
                              hipStream_t stream) {
    const float* colors = (const float*)d_in[0];
    const float* dlog   = (const float*)d_in[1];
    const float* depths = (const float*)d_in[2];
    float* out = (float*)d_out;

    dim3 grid(NRAY / (4 * RPW));   // 2048 blocks: 4 waves/block, 8 rays/wave
    dim3 block(256);
    hipLaunchKernelGGL(raymarch_kernel, grid, block, 0, stream, colors, dlog, depths, out);
}